// Round 14
// baseline (85.378 us; speedup 1.0000x reference)
//
#include <hip/hip_runtime.h>
#include <math.h>

#define NTOK 784
#define DIM 128
#define FFD 512

// ===== K_A: LN1 + qkv + (ekv,ek) -> T1/T2/S1/S2 atomics. grid 50, 256 thr =====
// block = (m-tile of 32 rows) x (d-half of 64). q written; ek/vv stay local.
__global__ __launch_bounds__(256) void lnqkv_T(
    const float* __restrict__ x, const float* __restrict__ g, const float* __restrict__ b,
    const float* __restrict__ wq, const float* __restrict__ wk, const float* __restrict__ wv,
    const float* __restrict__ pv,
    float* __restrict__ q, float* __restrict__ T1, float* __restrict__ T2,
    float* __restrict__ S1, float* __restrict__ S2) {
  __shared__ float smem[17280];
  float (*Xs)[32] = (float(*)[32])smem;             // [128][32]
  float (*Bq)[64] = (float(*)[64])(smem + 4096);    // [64][64]
  float (*Vs)[129] = (float(*)[129])(smem + 8192);  // [32][129] raw pv rows
  float (*Ekv)[68] = (float(*)[68])(smem + 12416);  // [32][68]
  float (*Ekk)[68] = (float(*)[68])(smem + 14592);  // [32][68]
  float* redS = smem + 16768;
  float* redQ = smem + 17024;
  int tid = threadIdx.x;
  int m0 = (blockIdx.x % 25) * 32;
  int half = blockIdx.x / 25;
  int n0 = half * 64;

  // --- stage x tile (transpose from [C,N]) + Vs (pv rows, zero OOB) ---
  if (m0 + 32 <= NTOK) {
#pragma unroll
    for (int it = 0; it < 4; ++it) {
      int idx = it * 256 + tid;
      int c = idx >> 3, j4 = (idx & 7) * 4;
      float4 v = *(const float4*)&x[c * NTOK + m0 + j4];
      Xs[c][j4 + 0] = v.x; Xs[c][j4 + 1] = v.y; Xs[c][j4 + 2] = v.z; Xs[c][j4 + 3] = v.w;
    }
  } else {
#pragma unroll
    for (int it = 0; it < 4; ++it) {
      int idx = it * 256 + tid;
      int c = idx >> 3, j4 = (idx & 7) * 4;
#pragma unroll
      for (int u = 0; u < 4; ++u) {
        int n = min(m0 + j4 + u, NTOK - 1);
        Xs[c][j4 + u] = x[c * NTOK + n];
      }
    }
  }
  {
    int m = tid >> 3, p16 = (tid & 7) * 16;
    int gm = m0 + m;
    if (gm < NTOK) {
#pragma unroll
      for (int w = 0; w < 4; ++w) {
        float4 v = *(const float4*)&pv[gm * DIM + p16 + w * 4];
        Vs[m][p16 + w * 4 + 0] = v.x; Vs[m][p16 + w * 4 + 1] = v.y;
        Vs[m][p16 + w * 4 + 2] = v.z; Vs[m][p16 + w * 4 + 3] = v.w;
      }
    } else {
#pragma unroll
      for (int w = 0; w < 16; ++w) Vs[m][p16 + w] = 0.f;
    }
  }
  __syncthreads();

  // --- LN1 over channels per column ---
  {
    int n = tid & 31, grp = tid >> 5;
    float s = 0.f, ss = 0.f;
    for (int c = grp * 16; c < grp * 16 + 16; ++c) { float v = Xs[c][n]; s += v; ss += v * v; }
    redS[grp * 32 + n] = s; redQ[grp * 32 + n] = ss;
    __syncthreads();
    float sum = 0.f, sq = 0.f;
#pragma unroll
    for (int gi = 0; gi < 8; ++gi) { sum += redS[gi * 32 + n]; sq += redQ[gi * 32 + n]; }
    float mu = sum * (1.0f / DIM);
    float var = sq * (1.0f / DIM) - mu * mu;
    float rs = rsqrtf(var + 1e-5f);
    for (int c = grp * 16; c < grp * 16 + 16; ++c)
      Xs[c][n] = (Xs[c][n] - mu) * rs * g[c] + b[c];
  }
  __syncthreads();

  int tx = tid & 15, ty = tid >> 4;   // 2 rows x 4 cols
  float ekr[2][4], ekvr[2][4];

  // --- mat k then v then q ---
#pragma unroll
  for (int mat = 0; mat < 3; ++mat) {
    const float* B = (mat == 0) ? wk : (mat == 1) ? wv : wq;
    float acc[2][4] = {};
#pragma unroll
    for (int h = 0; h < 2; ++h) {
      {
        int r = tid >> 2, kq = (tid & 3) * 16;
#pragma unroll
        for (int j = 0; j < 4; ++j) {
          float4 v = *(const float4*)&B[(n0 + r) * DIM + h * 64 + kq + j * 4];
          Bq[kq + j * 4 + 0][r] = v.x; Bq[kq + j * 4 + 1][r] = v.y;
          Bq[kq + j * 4 + 2][r] = v.z; Bq[kq + j * 4 + 3][r] = v.w;
        }
      }
      __syncthreads();
#pragma unroll 4
      for (int kk = 0; kk < 64; ++kk) {
        float2 a2 = *(const float2*)&Xs[h * 64 + kk][ty * 2];
        float4 b4 = *(const float4*)&Bq[kk][tx * 4];
        float av[2] = {a2.x, a2.y};
        float bv[4] = {b4.x, b4.y, b4.z, b4.w};
#pragma unroll
        for (int i = 0; i < 2; ++i)
#pragma unroll
          for (int j = 0; j < 4; ++j) acc[i][j] = fmaf(av[i], bv[j], acc[i][j]);
      }
      __syncthreads();
    }
    if (mat == 0) {
#pragma unroll
      for (int i = 0; i < 2; ++i)
#pragma unroll
        for (int j = 0; j < 4; ++j) ekr[i][j] = expf(acc[i][j]);
    } else if (mat == 1) {
#pragma unroll
      for (int i = 0; i < 2; ++i)
#pragma unroll
        for (int j = 0; j < 4; ++j) ekvr[i][j] = ekr[i][j] * acc[i][j];
      // store ek/ekv tiles (zero OOB rows)
#pragma unroll
      for (int i = 0; i < 2; ++i) {
        int lr = ty * 2 + i;
        bool ok = (m0 + lr) < NTOK;
#pragma unroll
        for (int j = 0; j < 4; ++j) {
          Ekv[lr][tx * 4 + j] = ok ? ekvr[i][j] : 0.f;
          Ekk[lr][tx * 4 + j] = ok ? ekr[i][j] : 0.f;
        }
      }
    } else {
#pragma unroll
      for (int i = 0; i < 2; ++i) {
        int gr = m0 + ty * 2 + i;
        if (gr < NTOK) {
          float4 o;
          o.x = 1.0f / (1.0f + expf(-acc[i][0]));
          o.y = 1.0f / (1.0f + expf(-acc[i][1]));
          o.z = 1.0f / (1.0f + expf(-acc[i][2]));
          o.w = 1.0f / (1.0f + expf(-acc[i][3]));
          *(float4*)&q[gr * DIM + n0 + tx * 4] = o;
        }
      }
    }
    __syncthreads();
  }

  // --- colsums -> S (Ekv/Ekk complete after mat==1 sync) ---
  if (tid < 64) {
    float s = 0.f;
#pragma unroll 8
    for (int m = 0; m < 32; ++m) s += Ekv[m][tid];
    atomicAdd(&S1[n0 + tid], s);
  } else if (tid < 128) {
    int c = tid - 64;
    float s = 0.f;
#pragma unroll 8
    for (int m = 0; m < 32; ++m) s += Ekk[m][c];
    atomicAdd(&S2[n0 + c], s);
  }

  // --- T contributions: T[p][d] += sum_m Vs[m][p] * {Ekv|Ekk}[m][d] ---
  {
    int py = tid >> 3;            // 0..31, p = py + 32u
    int dx = (tid & 7) * 8;       // 8 d per thread
    float t[4][8] = {};
    for (int m = 0; m < 32; ++m) {
      float a0 = Vs[m][py], a1 = Vs[m][py + 32], a2 = Vs[m][py + 64], a3 = Vs[m][py + 96];
      float4 e0 = *(const float4*)&Ekv[m][dx];
      float4 e1 = *(const float4*)&Ekv[m][dx + 4];
      float ev[8] = {e0.x, e0.y, e0.z, e0.w, e1.x, e1.y, e1.z, e1.w};
      float av[4] = {a0, a1, a2, a3};
#pragma unroll
      for (int u = 0; u < 4; ++u)
#pragma unroll
        for (int j = 0; j < 8; ++j) t[u][j] = fmaf(av[u], ev[j], t[u][j]);
    }
#pragma unroll
    for (int u = 0; u < 4; ++u)
#pragma unroll
      for (int j = 0; j < 8; ++j)
        atomicAdd(&T1[(py + 32 * u) * DIM + n0 + dx + j], t[u][j]);

    float t2a[4][8] = {};
    for (int m = 0; m < 32; ++m) {
      float a0 = Vs[m][py], a1 = Vs[m][py + 32], a2 = Vs[m][py + 64], a3 = Vs[m][py + 96];
      float4 e0 = *(const float4*)&Ekk[m][dx];
      float4 e1 = *(const float4*)&Ekk[m][dx + 4];
      float ev[8] = {e0.x, e0.y, e0.z, e0.w, e1.x, e1.y, e1.z, e1.w};
      float av[4] = {a0, a1, a2, a3};
#pragma unroll
      for (int u = 0; u < 4; ++u)
#pragma unroll
        for (int j = 0; j < 8; ++j) t2a[u][j] = fmaf(av[u], ev[j], t2a[u][j]);
    }
#pragma unroll
    for (int u = 0; u < 4; ++u)
#pragma unroll
      for (int j = 0; j < 8; ++j)
        atomicAdd(&T2[(py + 32 * u) * DIM + n0 + dx + j], t2a[u][j]);
  }
}

// ===== K_C: num/den = S + u@T; gate; proj; residual; LN2; out-init. grid 98 =====
__global__ __launch_bounds__(256) void gate_proj_ln_T(
    const float* __restrict__ pu, const float* __restrict__ T1, const float* __restrict__ T2,
    const float* __restrict__ S1, const float* __restrict__ S2,
    const float* __restrict__ q, const float* __restrict__ wo,
    const float* __restrict__ bo, const float* __restrict__ x,
    const float* __restrict__ g2, const float* __restrict__ b2n,
    const float* __restrict__ b2f, float* __restrict__ fn, float* __restrict__ out) {
  __shared__ float Wbuf[16384];    // Ts1[128][64] + Ts2[128][64]; then wo [128][128]
  __shared__ float At[DIM][9];
  __shared__ float u_s[8][DIM];
  int tid = threadIdx.x;
  int m0 = blockIdx.x * 8;

  {
    int r = tid >> 5, c4 = (tid & 31) * 4;
    float4 v = *(const float4*)&pu[(m0 + r) * DIM + c4];
    u_s[r][c4] = v.x; u_s[r][c4 + 1] = v.y; u_s[r][c4 + 2] = v.z; u_s[r][c4 + 3] = v.w;
  }

  float (*Ts1)[64] = (float(*)[64])Wbuf;
  float (*Ts2)[64] = (float(*)[64])(Wbuf + 8192);
#pragma unroll
  for (int h = 0; h < 2; ++h) {
    {
      int p = tid >> 1, dq = (tid & 1) * 32;
#pragma unroll
      for (int j = 0; j < 8; ++j) {
        float4 v = *(const float4*)&T1[p * DIM + h * 64 + dq + j * 4];
        *(float4*)&Ts1[p][dq + j * 4] = v;
        float4 w = *(const float4*)&T2[p * DIM + h * 64 + dq + j * 4];
        *(float4*)&Ts2[p][dq + j * 4] = w;
      }
    }
    __syncthreads();
    {
      int row = tid >> 5, d2 = (tid & 31) * 2;
      int dg = h * 64 + d2;
      float num0 = S1[dg], num1 = S1[dg + 1];
      float den0 = S2[dg], den1 = S2[dg + 1];
#pragma unroll 4
      for (int k = 0; k < DIM; ++k) {
        float a = u_s[row][k];
        float2 t1v = *(const float2*)&Ts1[k][d2];
        float2 t2v = *(const float2*)&Ts2[k][d2];
        num0 = fmaf(a, t1v.x, num0); num1 = fmaf(a, t1v.y, num1);
        den0 = fmaf(a, t2v.x, den0); den1 = fmaf(a, t2v.y, den1);
      }
      float2 qv = *(const float2*)&q[(m0 + row) * DIM + dg];
      At[dg][row] = qv.x * (num0 / den0);
      At[dg + 1][row] = qv.y * (num1 / den1);
    }
    __syncthreads();
  }

  // stage wo k-major, proj, residual, LN2, out-init (proven R8 path)
  float (*Bs)[DIM] = (float(*)[DIM])Wbuf;
  {
    int r = tid >> 1, kq = (tid & 1) * 64;
#pragma unroll
    for (int j = 0; j < 16; ++j) {
      float4 v = *(const float4*)&wo[r * DIM + kq + j * 4];
      Bs[kq + j * 4 + 0][r] = v.x; Bs[kq + j * 4 + 1][r] = v.y;
      Bs[kq + j * 4 + 2][r] = v.z; Bs[kq + j * 4 + 3][r] = v.w;
    }
  }
  __syncthreads();

  int ty = tid >> 5, txl = tid & 31;
  float acc[4] = {0.f, 0.f, 0.f, 0.f};
#pragma unroll 4
  for (int kk = 0; kk < DIM; ++kk) {
    float a = At[kk][ty];
    float4 b4 = *(const float4*)&Bs[kk][txl * 4];
    acc[0] = fmaf(a, b4.x, acc[0]);
    acc[1] = fmaf(a, b4.y, acc[1]);
    acc[2] = fmaf(a, b4.z, acc[2]);
    acc[3] = fmaf(a, b4.w, acc[3]);
  }
  int gn = m0 + ty;
  int c0 = txl * 4;
  float4 bias = *(const float4*)&bo[c0];
  float o0 = acc[0] + bias.x + x[(c0 + 0) * NTOK + gn];
  float o1 = acc[1] + bias.y + x[(c0 + 1) * NTOK + gn];
  float o2 = acc[2] + bias.z + x[(c0 + 2) * NTOK + gn];
  float o3 = acc[3] + bias.w + x[(c0 + 3) * NTOK + gn];

  float4 bf = *(const float4*)&b2f[c0];
  out[(c0 + 0) * NTOK + gn] = o0 + bf.x;
  out[(c0 + 1) * NTOK + gn] = o1 + bf.y;
  out[(c0 + 2) * NTOK + gn] = o2 + bf.z;
  out[(c0 + 3) * NTOK + gn] = o3 + bf.w;

  float s = o0 + o1 + o2 + o3;
  float ss = o0 * o0 + o1 * o1 + o2 * o2 + o3 * o3;
#pragma unroll
  for (int off = 1; off < 32; off <<= 1) {
    s += __shfl_xor(s, off);
    ss += __shfl_xor(ss, off);
  }
  float mu = s * (1.0f / DIM);
  float var = ss * (1.0f / DIM) - mu * mu;
  float rs = rsqrtf(var + 1e-5f);
  float4 gg = *(const float4*)&g2[c0];
  float4 bb = *(const float4*)&b2n[c0];
  float4 f;
  f.x = (o0 - mu) * rs * gg.x + bb.x;
  f.y = (o1 - mu) * rs * gg.y + bb.y;
  f.z = (o2 - mu) * rs * gg.z + bb.z;
  f.w = (o3 - mu) * rs * gg.w + bb.w;
  *(float4*)&fn[gn * DIM + c0] = f;
}

// ===== K_D: ff1(gelu)+ff2 fused, grid (49,8), 256 thr, atomic accumulate =====
__global__ __launch_bounds__(256) void ff_fused16(
    const float* __restrict__ fn, const float* __restrict__ w1,
    const float* __restrict__ b1f, const float* __restrict__ w2,
    float* __restrict__ out) {
  __shared__ float Fs[DIM][16];
  __shared__ float W1s[DIM][64];   // reused as W2s[64][128]
  __shared__ float P[16][65];
  int tid = threadIdx.x;
  int m0 = blockIdx.x * 16, f0 = blockIdx.y * 64;

  {
    int r = tid >> 4, kq = (tid & 15) * 8;
#pragma unroll
    for (int j = 0; j < 2; ++j) {
      float4 v = *(const float4*)&fn[(m0 + r) * DIM + kq + j * 4];
      Fs[kq + j * 4 + 0][r] = v.x; Fs[kq + j * 4 + 1][r] = v.y;
      Fs[kq + j * 4 + 2][r] = v.z; Fs[kq + j * 4 + 3][r] = v.w;
    }
    int rw = tid >> 2, kw = (tid & 3) * 32;
#pragma unroll
    for (int j = 0; j < 8; ++j) {
      float4 v = *(const float4*)&w1[(f0 + rw) * DIM + kw + j * 4];
      W1s[kw + j * 4 + 0][rw] = v.x; W1s[kw + j * 4 + 1][rw] = v.y;
      W1s[kw + j * 4 + 2][rw] = v.z; W1s[kw + j * 4 + 3][rw] = v.w;
    }
  }
  __syncthreads();

  int row = tid >> 4, f4 = (tid & 15) * 4;
  float acc1[4] = {};
#pragma unroll 4
  for (int kk = 0; kk < DIM; ++kk) {
    float a = Fs[kk][row];
    float4 b4 = *(const float4*)&W1s[kk][f4];
    acc1[0] = fmaf(a, b4.x, acc1[0]);
    acc1[1] = fmaf(a, b4.y, acc1[1]);
    acc1[2] = fmaf(a, b4.z, acc1[2]);
    acc1[3] = fmaf(a, b4.w, acc1[3]);
  }
  float4 b1v = *(const float4*)&b1f[f0 + f4];
  float bb[4] = {b1v.x, b1v.y, b1v.z, b1v.w};
  float ge[4];
#pragma unroll
  for (int j = 0; j < 4; ++j) {
    float v = acc1[j] + bb[j];
    ge[j] = 0.5f * v * (1.0f + erff(v * 0.70710678118654752f));
  }
  __syncthreads();

#pragma unroll
  for (int j = 0; j < 4; ++j) P[row][f4 + j] = ge[j];
  float* W2s = &W1s[0][0];
  {
    int c = tid >> 1, fq = (tid & 1) * 32;
#pragma unroll
    for (int j = 0; j < 8; ++j) {
      float4 v = *(const float4*)&w2[c * FFD + f0 + fq + j * 4];
      W2s[(fq + j * 4 + 0) * DIM + c] = v.x;
      W2s[(fq + j * 4 + 1) * DIM + c] = v.y;
      W2s[(fq + j * 4 + 2) * DIM + c] = v.z;
      W2s[(fq + j * 4 + 3) * DIM + c] = v.w;
    }
  }
  __syncthreads();

  int r2 = tid & 15, cb = (tid >> 4) * 8;
  float acc2[8] = {};
  for (int f = 0; f < 64; ++f) {
    float pvv = P[r2][f];
    const float* wr = &W2s[f * DIM + cb];
#pragma unroll
    for (int j4 = 0; j4 < 2; ++j4) {
      float4 wv = *(const float4*)&wr[j4 * 4];
      acc2[j4 * 4 + 0] = fmaf(pvv, wv.x, acc2[j4 * 4 + 0]);
      acc2[j4 * 4 + 1] = fmaf(pvv, wv.y, acc2[j4 * 4 + 1]);
      acc2[j4 * 4 + 2] = fmaf(pvv, wv.z, acc2[j4 * 4 + 2]);
      acc2[j4 * 4 + 3] = fmaf(pvv, wv.w, acc2[j4 * 4 + 3]);
    }
  }
#pragma unroll
  for (int j = 0; j < 8; ++j)
    atomicAdd(&out[(cb + j) * NTOK + m0 + r2], acc2[j]);
}

extern "C" void kernel_launch(void* const* d_in, const int* in_sizes, int n_in,
                              void* d_out, int out_size, void* d_ws, size_t ws_size,
                              hipStream_t stream) {
  const float* x   = (const float*)d_in[0];
  const float* wq  = (const float*)d_in[1];
  const float* wk  = (const float*)d_in[2];
  const float* wv  = (const float*)d_in[3];
  const float* wo  = (const float*)d_in[4];
  const float* bo  = (const float*)d_in[5];
  const float* pu  = (const float*)d_in[6];
  const float* pv  = (const float*)d_in[7];
  const float* g1  = (const float*)d_in[8];
  const float* b1n = (const float*)d_in[9];
  const float* g2  = (const float*)d_in[10];
  const float* b2n = (const float*)d_in[11];
  const float* w1  = (const float*)d_in[12];
  const float* b1f = (const float*)d_in[13];
  const float* w2  = (const float*)d_in[14];
  const float* b2f = (const float*)d_in[15];
  float* out = (float*)d_out;

  float* ws = (float*)d_ws;
  float* T1 = ws;                  // [128,128]
  float* T2 = ws + 16384;          // [128,128]
  float* S1 = ws + 32768;          // [128]
  float* S2 = ws + 32896;          // [128]
  float* q  = ws + 33024;          // [784,128]
  float* fn = ws + 133376;         // [784,128]

  hipMemsetAsync(ws, 0, 33024 * sizeof(float), stream);
  lnqkv_T<<<50, 256, 0, stream>>>(x, g1, b1n, wq, wk, wv, pv, q, T1, T2, S1, S2);
  gate_proj_ln_T<<<98, 256, 0, stream>>>(pu, T1, T2, S1, S2, q, wo, bo, x,
                                         g2, b2n, b2f, fn, out);
  ff_fused16<<<dim3(49, 8), 256, 0, stream>>>(fn, w1, b1f, w2, out);
}

// Round 15
// 84.341 us; speedup vs baseline: 1.0123x; 1.0123x over previous
//
#include <hip/hip_runtime.h>
#include <math.h>

#define NTOK 784
#define DIM 128
#define FFD 512

// ===== K_A: LN1 + qkv (R8's proven path, posw deleted). grid 150, 256 thr =====
__global__ __launch_bounds__(256) void lnqkv(
    const float* __restrict__ x, const float* __restrict__ g, const float* __restrict__ b,
    const float* __restrict__ wq, const float* __restrict__ wk, const float* __restrict__ wv,
    float* __restrict__ q, float* __restrict__ ek, float* __restrict__ vv) {
  __shared__ float smem[8704];
  float (*Xs)[32] = (float(*)[32])smem;            // [128][32]
  float (*Bq)[64] = (float(*)[64])(smem + 4096);   // [64][64]
  float* redS = smem + 8192;
  float* redQ = smem + 8448;
  int tid = threadIdx.x;
  int bid = blockIdx.x;
  int m0 = (bid % 25) * 32;
  int ct = bid / 25;
  int wsel = ct >> 1;
  int n0 = (ct & 1) * 64;
  const float* B = (wsel == 0) ? wq : (wsel == 1) ? wk : wv;

  if (m0 + 32 <= NTOK) {
#pragma unroll
    for (int it = 0; it < 4; ++it) {
      int idx = it * 256 + tid;
      int c = idx >> 3, j4 = (idx & 7) * 4;
      float4 v = *(const float4*)&x[c * NTOK + m0 + j4];
      Xs[c][j4 + 0] = v.x; Xs[c][j4 + 1] = v.y; Xs[c][j4 + 2] = v.z; Xs[c][j4 + 3] = v.w;
    }
  } else {
#pragma unroll
    for (int it = 0; it < 4; ++it) {
      int idx = it * 256 + tid;
      int c = idx >> 3, j4 = (idx & 7) * 4;
#pragma unroll
      for (int u = 0; u < 4; ++u) {
        int n = min(m0 + j4 + u, NTOK - 1);
        Xs[c][j4 + u] = x[c * NTOK + n];
      }
    }
  }
  __syncthreads();

  int n = tid & 31, grp = tid >> 5;
  float s = 0.f, ss = 0.f;
  for (int c = grp * 16; c < grp * 16 + 16; ++c) { float v = Xs[c][n]; s += v; ss += v * v; }
  redS[grp * 32 + n] = s; redQ[grp * 32 + n] = ss;
  __syncthreads();
  float sum = 0.f, sq = 0.f;
#pragma unroll
  for (int gi = 0; gi < 8; ++gi) { sum += redS[gi * 32 + n]; sq += redQ[gi * 32 + n]; }
  float mu = sum * (1.0f / DIM);
  float var = sq * (1.0f / DIM) - mu * mu;
  float rs = rsqrtf(var + 1e-5f);
  for (int c = grp * 16; c < grp * 16 + 16; ++c)
    Xs[c][n] = (Xs[c][n] - mu) * rs * g[c] + b[c];

  int tx = tid & 15, ty = tid >> 4;
  float acc[2][4] = {};
#pragma unroll
  for (int h = 0; h < 2; ++h) {
    {
      int r = tid >> 2, kq = (tid & 3) * 16;
#pragma unroll
      for (int j = 0; j < 4; ++j) {
        float4 v = *(const float4*)&B[(n0 + r) * DIM + h * 64 + kq + j * 4];
        Bq[kq + j * 4 + 0][r] = v.x; Bq[kq + j * 4 + 1][r] = v.y;
        Bq[kq + j * 4 + 2][r] = v.z; Bq[kq + j * 4 + 3][r] = v.w;
      }
    }
    __syncthreads();
#pragma unroll 4
    for (int kk = 0; kk < 64; ++kk) {
      float2 a2 = *(const float2*)&Xs[h * 64 + kk][ty * 2];
      float4 b4 = *(const float4*)&Bq[kk][tx * 4];
      float av[2] = {a2.x, a2.y};
      float bv[4] = {b4.x, b4.y, b4.z, b4.w};
#pragma unroll
      for (int i = 0; i < 2; ++i)
#pragma unroll
        for (int j = 0; j < 4; ++j) acc[i][j] = fmaf(av[i], bv[j], acc[i][j]);
    }
    __syncthreads();
  }
  int c0 = n0 + tx * 4;
  float* dst = (wsel == 0) ? q : (wsel == 1) ? ek : vv;
#pragma unroll
  for (int i = 0; i < 2; ++i) {
    int gr = m0 + ty * 2 + i;
    if (gr < NTOK) {
      float4 o;
      if (wsel == 0) {
        o.x = 1.0f / (1.0f + expf(-acc[i][0]));
        o.y = 1.0f / (1.0f + expf(-acc[i][1]));
        o.z = 1.0f / (1.0f + expf(-acc[i][2]));
        o.w = 1.0f / (1.0f + expf(-acc[i][3]));
      } else if (wsel == 1) {
        o.x = expf(acc[i][0]); o.y = expf(acc[i][1]);
        o.z = expf(acc[i][2]); o.w = expf(acc[i][3]);
      } else {
        o.x = acc[i][0]; o.y = acc[i][1]; o.z = acc[i][2]; o.w = acc[i][3];
      }
      *(float4*)&dst[gr * DIM + c0] = o;
    }
  }
}

// ===== K_B: T-partials: Tp1[s] = pv^T@(ek*vv) tile, Tp2[s] = pv^T@ek tile =====
// grid (2,2,4), 256 thr. Plain stores (no atomics). S colsums from bx==0 blocks.
__global__ __launch_bounds__(256) void t_build(
    const float* __restrict__ ek, const float* __restrict__ vv,
    const float* __restrict__ pv, float* __restrict__ Tp1, float* __restrict__ Tp2,
    float* __restrict__ Sp1, float* __restrict__ Sp2) {
  __shared__ float Ps[32][64];
  __shared__ float En[32][64];
  __shared__ float Ed[32][64];
  int tid = threadIdx.x;
  int p0 = blockIdx.x * 64, d0 = blockIdx.y * 64, sp = blockIdx.z;
  int klo = sp * 196, khi = klo + 196;
  int tx = tid & 15, ty = tid >> 4;
  float t1[4][4] = {}, t2[4][4] = {};
  float s1[4] = {}, s2[4] = {};
  int kb = tid >> 3, jb = (tid & 7) * 8;
  for (int k0 = klo; k0 < khi; k0 += 32) {
    int nk = min(32, khi - k0);
    if (kb < nk) {
      int gk = k0 + kb;
      float4 pa = *(const float4*)&pv[gk * DIM + p0 + jb];
      float4 pb = *(const float4*)&pv[gk * DIM + p0 + jb + 4];
      *(float4*)&Ps[kb][jb] = pa; *(float4*)&Ps[kb][jb + 4] = pb;
      float4 e0 = *(const float4*)&ek[gk * DIM + d0 + jb];
      float4 e1 = *(const float4*)&ek[gk * DIM + d0 + jb + 4];
      float4 v0 = *(const float4*)&vv[gk * DIM + d0 + jb];
      float4 v1 = *(const float4*)&vv[gk * DIM + d0 + jb + 4];
      *(float4*)&Ed[kb][jb] = e0; *(float4*)&Ed[kb][jb + 4] = e1;
      float4 n0v = {e0.x * v0.x, e0.y * v0.y, e0.z * v0.z, e0.w * v0.w};
      float4 n1v = {e1.x * v1.x, e1.y * v1.y, e1.z * v1.z, e1.w * v1.w};
      *(float4*)&En[kb][jb] = n0v; *(float4*)&En[kb][jb + 4] = n1v;
    } else {
      float4 z = {0.f, 0.f, 0.f, 0.f};
      *(float4*)&Ps[kb][jb] = z; *(float4*)&Ps[kb][jb + 4] = z;
      *(float4*)&Ed[kb][jb] = z; *(float4*)&Ed[kb][jb + 4] = z;
      *(float4*)&En[kb][jb] = z; *(float4*)&En[kb][jb + 4] = z;
    }
    __syncthreads();
#pragma unroll 8
    for (int kk = 0; kk < 32; ++kk) {
      float4 a4 = *(const float4*)&Ps[kk][ty * 4];
      float4 n4 = *(const float4*)&En[kk][tx * 4];
      float4 d4 = *(const float4*)&Ed[kk][tx * 4];
      float av[4] = {a4.x, a4.y, a4.z, a4.w};
      float nv[4] = {n4.x, n4.y, n4.z, n4.w};
      float dv[4] = {d4.x, d4.y, d4.z, d4.w};
#pragma unroll
      for (int i = 0; i < 4; ++i)
#pragma unroll
        for (int j = 0; j < 4; ++j) {
          t1[i][j] = fmaf(av[i], nv[j], t1[i][j]);
          t2[i][j] = fmaf(av[i], dv[j], t2[i][j]);
        }
      if (ty == 0) {
#pragma unroll
        for (int j = 0; j < 4; ++j) { s1[j] += nv[j]; s2[j] += dv[j]; }
      }
    }
    __syncthreads();
  }
#pragma unroll
  for (int i = 0; i < 4; ++i) {
    float4 o1 = {t1[i][0], t1[i][1], t1[i][2], t1[i][3]};
    float4 o2 = {t2[i][0], t2[i][1], t2[i][2], t2[i][3]};
    *(float4*)&Tp1[(sp * DIM + p0 + ty * 4 + i) * DIM + d0 + tx * 4] = o1;
    *(float4*)&Tp2[(sp * DIM + p0 + ty * 4 + i) * DIM + d0 + tx * 4] = o2;
  }
  if (ty == 0 && blockIdx.x == 0) {
    float4 o1 = {s1[0], s1[1], s1[2], s1[3]};
    float4 o2 = {s2[0], s2[1], s2[2], s2[3]};
    *(float4*)&Sp1[sp * DIM + d0 + tx * 4] = o1;
    *(float4*)&Sp2[sp * DIM + d0 + tx * 4] = o2;
  }
}

// ===== K_C: num/den = S + u@T (sum 4 partials); gate; proj; LN2; out-init =====
__global__ __launch_bounds__(256) void gate_proj_ln_T(
    const float* __restrict__ pu, const float* __restrict__ Tp1,
    const float* __restrict__ Tp2, const float* __restrict__ Sp1,
    const float* __restrict__ Sp2, const float* __restrict__ q,
    const float* __restrict__ wo, const float* __restrict__ bo,
    const float* __restrict__ x, const float* __restrict__ g2,
    const float* __restrict__ b2n, const float* __restrict__ b2f,
    float* __restrict__ fn, float* __restrict__ out) {
  __shared__ float Wbuf[16384];    // Ts1[128][64]+Ts2[128][64]; then wo [128][128]
  __shared__ float At[DIM][9];
  __shared__ float u_s[8][DIM];
  int tid = threadIdx.x;
  int m0 = blockIdx.x * 8;

  {
    int r = tid >> 5, c4 = (tid & 31) * 4;
    float4 v = *(const float4*)&pu[(m0 + r) * DIM + c4];
    u_s[r][c4] = v.x; u_s[r][c4 + 1] = v.y; u_s[r][c4 + 2] = v.z; u_s[r][c4 + 3] = v.w;
  }

  float (*Ts1)[64] = (float(*)[64])Wbuf;
  float (*Ts2)[64] = (float(*)[64])(Wbuf + 8192);
#pragma unroll
  for (int h = 0; h < 2; ++h) {
    {
      int p = tid >> 1, dq = (tid & 1) * 32;
#pragma unroll
      for (int j = 0; j < 8; ++j) {
        int off = p * DIM + h * 64 + dq + j * 4;
        float4 a0 = *(const float4*)&Tp1[off];
        float4 a1 = *(const float4*)&Tp1[DIM * DIM + off];
        float4 a2 = *(const float4*)&Tp1[2 * DIM * DIM + off];
        float4 a3 = *(const float4*)&Tp1[3 * DIM * DIM + off];
        float4 r1 = {a0.x + a1.x + a2.x + a3.x, a0.y + a1.y + a2.y + a3.y,
                     a0.z + a1.z + a2.z + a3.z, a0.w + a1.w + a2.w + a3.w};
        *(float4*)&Ts1[p][dq + j * 4] = r1;
        float4 b0 = *(const float4*)&Tp2[off];
        float4 b1 = *(const float4*)&Tp2[DIM * DIM + off];
        float4 b2 = *(const float4*)&Tp2[2 * DIM * DIM + off];
        float4 b3 = *(const float4*)&Tp2[3 * DIM * DIM + off];
        float4 r2 = {b0.x + b1.x + b2.x + b3.x, b0.y + b1.y + b2.y + b3.y,
                     b0.z + b1.z + b2.z + b3.z, b0.w + b1.w + b2.w + b3.w};
        *(float4*)&Ts2[p][dq + j * 4] = r2;
      }
    }
    __syncthreads();
    {
      int row = tid >> 5, d2 = (tid & 31) * 2;
      int dg = h * 64 + d2;
      float num0 = Sp1[dg] + Sp1[DIM + dg] + Sp1[2 * DIM + dg] + Sp1[3 * DIM + dg];
      float num1 = Sp1[dg + 1] + Sp1[DIM + dg + 1] + Sp1[2 * DIM + dg + 1] + Sp1[3 * DIM + dg + 1];
      float den0 = Sp2[dg] + Sp2[DIM + dg] + Sp2[2 * DIM + dg] + Sp2[3 * DIM + dg];
      float den1 = Sp2[dg + 1] + Sp2[DIM + dg + 1] + Sp2[2 * DIM + dg + 1] + Sp2[3 * DIM + dg + 1];
#pragma unroll 4
      for (int k = 0; k < DIM; ++k) {
        float a = u_s[row][k];
        float2 t1v = *(const float2*)&Ts1[k][d2];
        float2 t2v = *(const float2*)&Ts2[k][d2];
        num0 = fmaf(a, t1v.x, num0); num1 = fmaf(a, t1v.y, num1);
        den0 = fmaf(a, t2v.x, den0); den1 = fmaf(a, t2v.y, den1);
      }
      float2 qv = *(const float2*)&q[(m0 + row) * DIM + dg];
      At[dg][row] = qv.x * (num0 / den0);
      At[dg + 1][row] = qv.y * (num1 / den1);
    }
    __syncthreads();
  }

  float (*Bs)[DIM] = (float(*)[DIM])Wbuf;
  {
    int r = tid >> 1, kq = (tid & 1) * 64;
#pragma unroll
    for (int j = 0; j < 16; ++j) {
      float4 v = *(const float4*)&wo[r * DIM + kq + j * 4];
      Bs[kq + j * 4 + 0][r] = v.x; Bs[kq + j * 4 + 1][r] = v.y;
      Bs[kq + j * 4 + 2][r] = v.z; Bs[kq + j * 4 + 3][r] = v.w;
    }
  }
  __syncthreads();

  int ty = tid >> 5, txl = tid & 31;
  float acc[4] = {0.f, 0.f, 0.f, 0.f};
#pragma unroll 4
  for (int kk = 0; kk < DIM; ++kk) {
    float a = At[kk][ty];
    float4 b4 = *(const float4*)&Bs[kk][txl * 4];
    acc[0] = fmaf(a, b4.x, acc[0]);
    acc[1] = fmaf(a, b4.y, acc[1]);
    acc[2] = fmaf(a, b4.z, acc[2]);
    acc[3] = fmaf(a, b4.w, acc[3]);
  }
  int gn = m0 + ty;
  int c0 = txl * 4;
  float4 bias = *(const float4*)&bo[c0];
  float o0 = acc[0] + bias.x + x[(c0 + 0) * NTOK + gn];
  float o1 = acc[1] + bias.y + x[(c0 + 1) * NTOK + gn];
  float o2 = acc[2] + bias.z + x[(c0 + 2) * NTOK + gn];
  float o3 = acc[3] + bias.w + x[(c0 + 3) * NTOK + gn];

  float4 bf = *(const float4*)&b2f[c0];
  out[(c0 + 0) * NTOK + gn] = o0 + bf.x;
  out[(c0 + 1) * NTOK + gn] = o1 + bf.y;
  out[(c0 + 2) * NTOK + gn] = o2 + bf.z;
  out[(c0 + 3) * NTOK + gn] = o3 + bf.w;

  float s = o0 + o1 + o2 + o3;
  float ss = o0 * o0 + o1 * o1 + o2 * o2 + o3 * o3;
#pragma unroll
  for (int off = 1; off < 32; off <<= 1) {
    s += __shfl_xor(s, off);
    ss += __shfl_xor(ss, off);
  }
  float mu = s * (1.0f / DIM);
  float var = ss * (1.0f / DIM) - mu * mu;
  float rs = rsqrtf(var + 1e-5f);
  float4 gg = *(const float4*)&g2[c0];
  float4 bb = *(const float4*)&b2n[c0];
  float4 f;
  f.x = (o0 - mu) * rs * gg.x + bb.x;
  f.y = (o1 - mu) * rs * gg.y + bb.y;
  f.z = (o2 - mu) * rs * gg.z + bb.z;
  f.w = (o3 - mu) * rs * gg.w + bb.w;
  *(float4*)&fn[gn * DIM + c0] = f;
}

// ===== K_D: ff1(gelu)+ff2 fused, grid (49,8), 256 thr, atomic accumulate =====
__global__ __launch_bounds__(256) void ff_fused16(
    const float* __restrict__ fn, const float* __restrict__ w1,
    const float* __restrict__ b1f, const float* __restrict__ w2,
    float* __restrict__ out) {
  __shared__ float Fs[DIM][16];
  __shared__ float W1s[DIM][64];   // reused as W2s[64][128]
  __shared__ float P[16][65];
  int tid = threadIdx.x;
  int m0 = blockIdx.x * 16, f0 = blockIdx.y * 64;

  {
    int r = tid >> 4, kq = (tid & 15) * 8;
#pragma unroll
    for (int j = 0; j < 2; ++j) {
      float4 v = *(const float4*)&fn[(m0 + r) * DIM + kq + j * 4];
      Fs[kq + j * 4 + 0][r] = v.x; Fs[kq + j * 4 + 1][r] = v.y;
      Fs[kq + j * 4 + 2][r] = v.z; Fs[kq + j * 4 + 3][r] = v.w;
    }
    int rw = tid >> 2, kw = (tid & 3) * 32;
#pragma unroll
    for (int j = 0; j < 8; ++j) {
      float4 v = *(const float4*)&w1[(f0 + rw) * DIM + kw + j * 4];
      W1s[kw + j * 4 + 0][rw] = v.x; W1s[kw + j * 4 + 1][rw] = v.y;
      W1s[kw + j * 4 + 2][rw] = v.z; W1s[kw + j * 4 + 3][rw] = v.w;
    }
  }
  __syncthreads();

  int row = tid >> 4, f4 = (tid & 15) * 4;
  float acc1[4] = {};
#pragma unroll 4
  for (int kk = 0; kk < DIM; ++kk) {
    float a = Fs[kk][row];
    float4 b4 = *(const float4*)&W1s[kk][f4];
    acc1[0] = fmaf(a, b4.x, acc1[0]);
    acc1[1] = fmaf(a, b4.y, acc1[1]);
    acc1[2] = fmaf(a, b4.z, acc1[2]);
    acc1[3] = fmaf(a, b4.w, acc1[3]);
  }
  float4 b1v = *(const float4*)&b1f[f0 + f4];
  float bb[4] = {b1v.x, b1v.y, b1v.z, b1v.w};
  float ge[4];
#pragma unroll
  for (int j = 0; j < 4; ++j) {
    float v = acc1[j] + bb[j];
    ge[j] = 0.5f * v * (1.0f + erff(v * 0.70710678118654752f));
  }
  __syncthreads();

#pragma unroll
  for (int j = 0; j < 4; ++j) P[row][f4 + j] = ge[j];
  float* W2s = &W1s[0][0];
  {
    int c = tid >> 1, fq = (tid & 1) * 32;
#pragma unroll
    for (int j = 0; j < 8; ++j) {
      float4 v = *(const float4*)&w2[c * FFD + f0 + fq + j * 4];
      W2s[(fq + j * 4 + 0) * DIM + c] = v.x;
      W2s[(fq + j * 4 + 1) * DIM + c] = v.y;
      W2s[(fq + j * 4 + 2) * DIM + c] = v.z;
      W2s[(fq + j * 4 + 3) * DIM + c] = v.w;
    }
  }
  __syncthreads();

  int r2 = tid & 15, cb = (tid >> 4) * 8;
  float acc2[8] = {};
  for (int f = 0; f < 64; ++f) {
    float pvv = P[r2][f];
    const float* wr = &W2s[f * DIM + cb];
#pragma unroll
    for (int j4 = 0; j4 < 2; ++j4) {
      float4 wv = *(const float4*)&wr[j4 * 4];
      acc2[j4 * 4 + 0] = fmaf(pvv, wv.x, acc2[j4 * 4 + 0]);
      acc2[j4 * 4 + 1] = fmaf(pvv, wv.y, acc2[j4 * 4 + 1]);
      acc2[j4 * 4 + 2] = fmaf(pvv, wv.z, acc2[j4 * 4 + 2]);
      acc2[j4 * 4 + 3] = fmaf(pvv, wv.w, acc2[j4 * 4 + 3]);
    }
  }
#pragma unroll
  for (int j = 0; j < 8; ++j)
    atomicAdd(&out[(cb + j) * NTOK + m0 + r2], acc2[j]);
}

extern "C" void kernel_launch(void* const* d_in, const int* in_sizes, int n_in,
                              void* d_out, int out_size, void* d_ws, size_t ws_size,
                              hipStream_t stream) {
  const float* x   = (const float*)d_in[0];
  const float* wq  = (const float*)d_in[1];
  const float* wk  = (const float*)d_in[2];
  const float* wv  = (const float*)d_in[3];
  const float* wo  = (const float*)d_in[4];
  const float* bo  = (const float*)d_in[5];
  const float* pu  = (const float*)d_in[6];
  const float* pv  = (const float*)d_in[7];
  const float* g1  = (const float*)d_in[8];
  const float* b1n = (const float*)d_in[9];
  const float* g2  = (const float*)d_in[10];
  const float* b2n = (const float*)d_in[11];
  const float* w1  = (const float*)d_in[12];
  const float* b1f = (const float*)d_in[13];
  const float* w2  = (const float*)d_in[14];
  const float* b2f = (const float*)d_in[15];
  float* out = (float*)d_out;

  float* ws = (float*)d_ws;
  float* q   = ws;                  // [784,128]
  float* ek  = ws + 100352;         // [784,128]
  float* vv  = ws + 200704;         // [784,128]
  float* fn  = ws + 301056;         // [784,128]
  float* Tp1 = ws + 401408;         // [4,128,128]
  float* Tp2 = ws + 466944;         // [4,128,128]
  float* Sp1 = ws + 532480;         // [4,128]
  float* Sp2 = ws + 532992;         // [4,128]

  lnqkv<<<150, 256, 0, stream>>>(x, g1, b1n, wq, wk, wv, q, ek, vv);
  t_build<<<dim3(2, 2, 4), 256, 0, stream>>>(ek, vv, pv, Tp1, Tp2, Sp1, Sp2);
  gate_proj_ln_T<<<98, 256, 0, stream>>>(pu, Tp1, Tp2, Sp1, Sp2, q, wo, bo, x,
                                         g2, b2n, b2f, fn, out);
  ff_fused16<<<dim3(49, 8), 256, 0, stream>>>(fn, w1, b1f, w2, out);
}

// Round 16
// 71.190 us; speedup vs baseline: 1.1993x; 1.1847x over previous
//
#include <hip/hip_runtime.h>
#include <math.h>

#define NTOK 784
#define DIM 128
#define FFD 512

// ===== K_A: zero(T/S) + LN1 + qkv. grid 150, 256 thr =====
__global__ __launch_bounds__(256) void lnqkv(
    const float* __restrict__ x, const float* __restrict__ g, const float* __restrict__ b,
    const float* __restrict__ wq, const float* __restrict__ wk, const float* __restrict__ wv,
    float* __restrict__ q, float* __restrict__ ek, float* __restrict__ vv,
    float* __restrict__ Tz) {
  __shared__ float smem[8704];
  float (*Xs)[32] = (float(*)[32])smem;            // [128][32]
  float (*Bq)[64] = (float(*)[64])(smem + 4096);   // [64][64]
  float* redS = smem + 8192;
  float* redQ = smem + 8448;
  int tid = threadIdx.x;
  int bid = blockIdx.x;

  // zero T1,T2,S1,S2 (33024 floats, contiguous at Tz)
  for (int i = bid * 256 + tid; i < 33024; i += 150 * 256) Tz[i] = 0.f;

  int m0 = (bid % 25) * 32;
  int ct = bid / 25;
  int wsel = ct >> 1;
  int n0 = (ct & 1) * 64;
  const float* B = (wsel == 0) ? wq : (wsel == 1) ? wk : wv;

  if (m0 + 32 <= NTOK) {
#pragma unroll
    for (int it = 0; it < 4; ++it) {
      int idx = it * 256 + tid;
      int c = idx >> 3, j4 = (idx & 7) * 4;
      float4 v = *(const float4*)&x[c * NTOK + m0 + j4];
      Xs[c][j4 + 0] = v.x; Xs[c][j4 + 1] = v.y; Xs[c][j4 + 2] = v.z; Xs[c][j4 + 3] = v.w;
    }
  } else {
#pragma unroll
    for (int it = 0; it < 4; ++it) {
      int idx = it * 256 + tid;
      int c = idx >> 3, j4 = (idx & 7) * 4;
#pragma unroll
      for (int u = 0; u < 4; ++u) {
        int n = min(m0 + j4 + u, NTOK - 1);
        Xs[c][j4 + u] = x[c * NTOK + n];
      }
    }
  }
  __syncthreads();

  int n = tid & 31, grp = tid >> 5;
  float s = 0.f, ss = 0.f;
  for (int c = grp * 16; c < grp * 16 + 16; ++c) { float v = Xs[c][n]; s += v; ss += v * v; }
  redS[grp * 32 + n] = s; redQ[grp * 32 + n] = ss;
  __syncthreads();
  float sum = 0.f, sq = 0.f;
#pragma unroll
  for (int gi = 0; gi < 8; ++gi) { sum += redS[gi * 32 + n]; sq += redQ[gi * 32 + n]; }
  float mu = sum * (1.0f / DIM);
  float var = sq * (1.0f / DIM) - mu * mu;
  float rs = rsqrtf(var + 1e-5f);
  for (int c = grp * 16; c < grp * 16 + 16; ++c)
    Xs[c][n] = (Xs[c][n] - mu) * rs * g[c] + b[c];

  int tx = tid & 15, ty = tid >> 4;
  float acc[2][4] = {};
#pragma unroll
  for (int h = 0; h < 2; ++h) {
    {
      int r = tid >> 2, kq = (tid & 3) * 16;
#pragma unroll
      for (int j = 0; j < 4; ++j) {
        float4 v = *(const float4*)&B[(n0 + r) * DIM + h * 64 + kq + j * 4];
        Bq[kq + j * 4 + 0][r] = v.x; Bq[kq + j * 4 + 1][r] = v.y;
        Bq[kq + j * 4 + 2][r] = v.z; Bq[kq + j * 4 + 3][r] = v.w;
      }
    }
    __syncthreads();
#pragma unroll 4
    for (int kk = 0; kk < 64; ++kk) {
      float2 a2 = *(const float2*)&Xs[h * 64 + kk][ty * 2];
      float4 b4 = *(const float4*)&Bq[kk][tx * 4];
      float av[2] = {a2.x, a2.y};
      float bv[4] = {b4.x, b4.y, b4.z, b4.w};
#pragma unroll
      for (int i = 0; i < 2; ++i)
#pragma unroll
        for (int j = 0; j < 4; ++j) acc[i][j] = fmaf(av[i], bv[j], acc[i][j]);
    }
    __syncthreads();
  }
  int c0 = n0 + tx * 4;
  float* dst = (wsel == 0) ? q : (wsel == 1) ? ek : vv;
#pragma unroll
  for (int i = 0; i < 2; ++i) {
    int gr = m0 + ty * 2 + i;
    if (gr < NTOK) {
      float4 o;
      if (wsel == 0) {
        o.x = 1.0f / (1.0f + expf(-acc[i][0]));
        o.y = 1.0f / (1.0f + expf(-acc[i][1]));
        o.z = 1.0f / (1.0f + expf(-acc[i][2]));
        o.w = 1.0f / (1.0f + expf(-acc[i][3]));
      } else if (wsel == 1) {
        o.x = expf(acc[i][0]); o.y = expf(acc[i][1]);
        o.z = expf(acc[i][2]); o.w = expf(acc[i][3]);
      } else {
        o.x = acc[i][0]; o.y = acc[i][1]; o.z = acc[i][2]; o.w = acc[i][3];
      }
      *(float4*)&dst[gr * DIM + c0] = o;
    }
  }
}

// ===== K_B: T1 += pv^T@(ek*vv), T2 += pv^T@ek via atomics. grid (4,4,4), 256 thr =====
__global__ __launch_bounds__(256) void t_build(
    const float* __restrict__ ek, const float* __restrict__ vv,
    const float* __restrict__ pv, float* __restrict__ T1, float* __restrict__ T2,
    float* __restrict__ S1, float* __restrict__ S2) {
  __shared__ float Ps[32][36];
  __shared__ float En[32][36];
  __shared__ float Ed[32][36];
  int tid = threadIdx.x;
  int p0 = blockIdx.x * 32, d0 = blockIdx.y * 32, sp = blockIdx.z;
  int klo = sp * 196, khi = klo + 196;
  int kb = tid >> 3, jb = (tid & 7) * 4;
  int ty = tid >> 3, tx = tid & 7;     // p-row = ty, d4 = tx*4
  float t1[4] = {}, t2[4] = {}, s1[4] = {}, s2[4] = {};
  for (int k0 = klo; k0 < khi; k0 += 32) {
    int nk = khi - k0; if (nk > 32) nk = 32;
    if (kb < nk) {
      int gk = k0 + kb;
      *(float4*)&Ps[kb][jb] = *(const float4*)&pv[gk * DIM + p0 + jb];
      float4 e = *(const float4*)&ek[gk * DIM + d0 + jb];
      float4 v = *(const float4*)&vv[gk * DIM + d0 + jb];
      *(float4*)&Ed[kb][jb] = e;
      float4 nn = {e.x * v.x, e.y * v.y, e.z * v.z, e.w * v.w};
      *(float4*)&En[kb][jb] = nn;
    } else {
      float4 z = {0.f, 0.f, 0.f, 0.f};
      *(float4*)&Ps[kb][jb] = z; *(float4*)&Ed[kb][jb] = z; *(float4*)&En[kb][jb] = z;
    }
    __syncthreads();
#pragma unroll 8
    for (int kk = 0; kk < 32; ++kk) {
      float a = Ps[kk][ty];
      float4 n4 = *(const float4*)&En[kk][tx * 4];
      float4 d4 = *(const float4*)&Ed[kk][tx * 4];
      t1[0] = fmaf(a, n4.x, t1[0]); t1[1] = fmaf(a, n4.y, t1[1]);
      t1[2] = fmaf(a, n4.z, t1[2]); t1[3] = fmaf(a, n4.w, t1[3]);
      t2[0] = fmaf(a, d4.x, t2[0]); t2[1] = fmaf(a, d4.y, t2[1]);
      t2[2] = fmaf(a, d4.z, t2[2]); t2[3] = fmaf(a, d4.w, t2[3]);
      if (ty == 0) {
        s1[0] += n4.x; s1[1] += n4.y; s1[2] += n4.z; s1[3] += n4.w;
        s2[0] += d4.x; s2[1] += d4.y; s2[2] += d4.z; s2[3] += d4.w;
      }
    }
    __syncthreads();
  }
  int gp = p0 + ty;
  int gd = d0 + tx * 4;
#pragma unroll
  for (int j = 0; j < 4; ++j) {
    atomicAdd(&T1[gp * DIM + gd + j], t1[j]);
    atomicAdd(&T2[gp * DIM + gd + j], t2[j]);
  }
  if (ty == 0 && blockIdx.x == 0) {
#pragma unroll
    for (int j = 0; j < 4; ++j) {
      atomicAdd(&S1[gd + j], s1[j]);
      atomicAdd(&S2[gd + j], s2[j]);
    }
  }
}

// ===== K_C: num/den = S + u@T; gate; proj; residual; LN2; out-init. grid 98 =====
__global__ __launch_bounds__(256) void gate_proj_ln_T(
    const float* __restrict__ pu, const float* __restrict__ T1,
    const float* __restrict__ T2, const float* __restrict__ S1,
    const float* __restrict__ S2, const float* __restrict__ q,
    const float* __restrict__ wo, const float* __restrict__ bo,
    const float* __restrict__ x, const float* __restrict__ g2,
    const float* __restrict__ b2n, const float* __restrict__ b2f,
    float* __restrict__ fn, float* __restrict__ out) {
  __shared__ float Wbuf[16384];    // Ts1[128][64]+Ts2[128][64]; then wo [128][128]
  __shared__ float At[DIM][9];
  __shared__ float u_s[8][DIM];
  int tid = threadIdx.x;
  int m0 = blockIdx.x * 8;

  {
    int r = tid >> 5, c4 = (tid & 31) * 4;
    float4 v = *(const float4*)&pu[(m0 + r) * DIM + c4];
    u_s[r][c4] = v.x; u_s[r][c4 + 1] = v.y; u_s[r][c4 + 2] = v.z; u_s[r][c4 + 3] = v.w;
  }

  float (*Ts1)[64] = (float(*)[64])Wbuf;
  float (*Ts2)[64] = (float(*)[64])(Wbuf + 8192);
#pragma unroll
  for (int h = 0; h < 2; ++h) {
    {
      int p = tid >> 1, dq = (tid & 1) * 32;
#pragma unroll
      for (int j = 0; j < 8; ++j) {
        int off = p * DIM + h * 64 + dq + j * 4;
        *(float4*)&Ts1[p][dq + j * 4] = *(const float4*)&T1[off];
        *(float4*)&Ts2[p][dq + j * 4] = *(const float4*)&T2[off];
      }
    }
    __syncthreads();
    {
      int row = tid >> 5, d2 = (tid & 31) * 2;
      int dg = h * 64 + d2;
      float2 sv1 = *(const float2*)&S1[dg];
      float2 sv2 = *(const float2*)&S2[dg];
      float num0 = sv1.x, num1 = sv1.y;
      float den0 = sv2.x, den1 = sv2.y;
#pragma unroll 4
      for (int k = 0; k < DIM; ++k) {
        float a = u_s[row][k];
        float2 t1v = *(const float2*)&Ts1[k][d2];
        float2 t2v = *(const float2*)&Ts2[k][d2];
        num0 = fmaf(a, t1v.x, num0); num1 = fmaf(a, t1v.y, num1);
        den0 = fmaf(a, t2v.x, den0); den1 = fmaf(a, t2v.y, den1);
      }
      float2 qv = *(const float2*)&q[(m0 + row) * DIM + dg];
      At[dg][row] = qv.x * (num0 / den0);
      At[dg + 1][row] = qv.y * (num1 / den1);
    }
    __syncthreads();
  }

  float (*Bs)[DIM] = (float(*)[DIM])Wbuf;
  {
    int r = tid >> 1, kq = (tid & 1) * 64;
#pragma unroll
    for (int j = 0; j < 16; ++j) {
      float4 v = *(const float4*)&wo[r * DIM + kq + j * 4];
      Bs[kq + j * 4 + 0][r] = v.x; Bs[kq + j * 4 + 1][r] = v.y;
      Bs[kq + j * 4 + 2][r] = v.z; Bs[kq + j * 4 + 3][r] = v.w;
    }
  }
  __syncthreads();

  int ty = tid >> 5, txl = tid & 31;
  float acc[4] = {0.f, 0.f, 0.f, 0.f};
#pragma unroll 4
  for (int kk = 0; kk < DIM; ++kk) {
    float a = At[kk][ty];
    float4 b4 = *(const float4*)&Bs[kk][txl * 4];
    acc[0] = fmaf(a, b4.x, acc[0]);
    acc[1] = fmaf(a, b4.y, acc[1]);
    acc[2] = fmaf(a, b4.z, acc[2]);
    acc[3] = fmaf(a, b4.w, acc[3]);
  }
  int gn = m0 + ty;
  int c0 = txl * 4;
  float4 bias = *(const float4*)&bo[c0];
  float o0 = acc[0] + bias.x + x[(c0 + 0) * NTOK + gn];
  float o1 = acc[1] + bias.y + x[(c0 + 1) * NTOK + gn];
  float o2 = acc[2] + bias.z + x[(c0 + 2) * NTOK + gn];
  float o3 = acc[3] + bias.w + x[(c0 + 3) * NTOK + gn];

  float4 bf = *(const float4*)&b2f[c0];
  out[(c0 + 0) * NTOK + gn] = o0 + bf.x;
  out[(c0 + 1) * NTOK + gn] = o1 + bf.y;
  out[(c0 + 2) * NTOK + gn] = o2 + bf.z;
  out[(c0 + 3) * NTOK + gn] = o3 + bf.w;

  float s = o0 + o1 + o2 + o3;
  float ss = o0 * o0 + o1 * o1 + o2 * o2 + o3 * o3;
#pragma unroll
  for (int off = 1; off < 32; off <<= 1) {
    s += __shfl_xor(s, off);
    ss += __shfl_xor(ss, off);
  }
  float mu = s * (1.0f / DIM);
  float var = ss * (1.0f / DIM) - mu * mu;
  float rs = rsqrtf(var + 1e-5f);
  float4 gg = *(const float4*)&g2[c0];
  float4 bb = *(const float4*)&b2n[c0];
  float4 f;
  f.x = (o0 - mu) * rs * gg.x + bb.x;
  f.y = (o1 - mu) * rs * gg.y + bb.y;
  f.z = (o2 - mu) * rs * gg.z + bb.z;
  f.w = (o3 - mu) * rs * gg.w + bb.w;
  *(float4*)&fn[gn * DIM + c0] = f;
}

// ===== K_D: ff1(gelu)+ff2 fused, grid (49,8), 256 thr, atomic accumulate =====
__global__ __launch_bounds__(256) void ff_fused16(
    const float* __restrict__ fn, const float* __restrict__ w1,
    const float* __restrict__ b1f, const float* __restrict__ w2,
    float* __restrict__ out) {
  __shared__ float Fs[DIM][16];
  __shared__ float W1s[DIM][64];   // reused as W2s[64][128]
  __shared__ float P[16][65];
  int tid = threadIdx.x;
  int m0 = blockIdx.x * 16, f0 = blockIdx.y * 64;

  {
    int r = tid >> 4, kq = (tid & 15) * 8;
#pragma unroll
    for (int j = 0; j < 2; ++j) {
      float4 v = *(const float4*)&fn[(m0 + r) * DIM + kq + j * 4];
      Fs[kq + j * 4 + 0][r] = v.x; Fs[kq + j * 4 + 1][r] = v.y;
      Fs[kq + j * 4 + 2][r] = v.z; Fs[kq + j * 4 + 3][r] = v.w;
    }
    int rw = tid >> 2, kw = (tid & 3) * 32;
#pragma unroll
    for (int j = 0; j < 8; ++j) {
      float4 v = *(const float4*)&w1[(f0 + rw) * DIM + kw + j * 4];
      W1s[kw + j * 4 + 0][rw] = v.x; W1s[kw + j * 4 + 1][rw] = v.y;
      W1s[kw + j * 4 + 2][rw] = v.z; W1s[kw + j * 4 + 3][rw] = v.w;
    }
  }
  __syncthreads();

  int row = tid >> 4, f4 = (tid & 15) * 4;
  float acc1[4] = {};
#pragma unroll 4
  for (int kk = 0; kk < DIM; ++kk) {
    float a = Fs[kk][row];
    float4 b4 = *(const float4*)&W1s[kk][f4];
    acc1[0] = fmaf(a, b4.x, acc1[0]);
    acc1[1] = fmaf(a, b4.y, acc1[1]);
    acc1[2] = fmaf(a, b4.z, acc1[2]);
    acc1[3] = fmaf(a, b4.w, acc1[3]);
  }
  float4 b1v = *(const float4*)&b1f[f0 + f4];
  float bb[4] = {b1v.x, b1v.y, b1v.z, b1v.w};
  float ge[4];
#pragma unroll
  for (int j = 0; j < 4; ++j) {
    float v = acc1[j] + bb[j];
    ge[j] = 0.5f * v * (1.0f + erff(v * 0.70710678118654752f));
  }
  __syncthreads();

#pragma unroll
  for (int j = 0; j < 4; ++j) P[row][f4 + j] = ge[j];
  float* W2s = &W1s[0][0];
  {
    int c = tid >> 1, fq = (tid & 1) * 32;
#pragma unroll
    for (int j = 0; j < 8; ++j) {
      float4 v = *(const float4*)&w2[c * FFD + f0 + fq + j * 4];
      W2s[(fq + j * 4 + 0) * DIM + c] = v.x;
      W2s[(fq + j * 4 + 1) * DIM + c] = v.y;
      W2s[(fq + j * 4 + 2) * DIM + c] = v.z;
      W2s[(fq + j * 4 + 3) * DIM + c] = v.w;
    }
  }
  __syncthreads();

  int r2 = tid & 15, cb = (tid >> 4) * 8;
  float acc2[8] = {};
  for (int f = 0; f < 64; ++f) {
    float pvv = P[r2][f];
    const float* wr = &W2s[f * DIM + cb];
#pragma unroll
    for (int j4 = 0; j4 < 2; ++j4) {
      float4 wv = *(const float4*)&wr[j4 * 4];
      acc2[j4 * 4 + 0] = fmaf(pvv, wv.x, acc2[j4 * 4 + 0]);
      acc2[j4 * 4 + 1] = fmaf(pvv, wv.y, acc2[j4 * 4 + 1]);
      acc2[j4 * 4 + 2] = fmaf(pvv, wv.z, acc2[j4 * 4 + 2]);
      acc2[j4 * 4 + 3] = fmaf(pvv, wv.w, acc2[j4 * 4 + 3]);
    }
  }
#pragma unroll
  for (int j = 0; j < 8; ++j)
    atomicAdd(&out[(cb + j) * NTOK + m0 + r2], acc2[j]);
}

extern "C" void kernel_launch(void* const* d_in, const int* in_sizes, int n_in,
                              void* d_out, int out_size, void* d_ws, size_t ws_size,
                              hipStream_t stream) {
  const float* x   = (const float*)d_in[0];
  const float* wq  = (const float*)d_in[1];
  const float* wk  = (const float*)d_in[2];
  const float* wv  = (const float*)d_in[3];
  const float* wo  = (const float*)d_in[4];
  const float* bo  = (const float*)d_in[5];
  const float* pu  = (const float*)d_in[6];
  const float* pv  = (const float*)d_in[7];
  const float* g1  = (const float*)d_in[8];
  const float* b1n = (const float*)d_in[9];
  const float* g2  = (const float*)d_in[10];
  const float* b2n = (const float*)d_in[11];
  const float* w1  = (const float*)d_in[12];
  const float* b1f = (const float*)d_in[13];
  const float* w2  = (const float*)d_in[14];
  const float* b2f = (const float*)d_in[15];
  float* out = (float*)d_out;

  float* ws = (float*)d_ws;
  float* T1 = ws;                   // [128,128]
  float* T2 = ws + 16384;           // [128,128]
  float* S1 = ws + 32768;           // [128]
  float* S2 = ws + 32896;           // [128]
  float* q  = ws + 33024;           // [784,128]
  float* ek = ws + 133376;          // [784,128]
  float* vv = ws + 233728;          // [784,128]
  float* fn = ws + 334080;          // [784,128]

  lnqkv<<<150, 256, 0, stream>>>(x, g1, b1n, wq, wk, wv, q, ek, vv, ws);
  t_build<<<dim3(4, 4, 4), 256, 0, stream>>>(ek, vv, pv, T1, T2, S1, S2);
  gate_proj_ln_T<<<98, 256, 0, stream>>>(pu, T1, T2, S1, S2, q, wo, bo, x,
                                         g2, b2n, b2f, fn, out);
  ff_fused16<<<dim3(49, 8), 256, 0, stream>>>(fn, w1, b1f, w2, out);
}